// Round 6
// baseline (118.611 us; speedup 1.0000x reference)
//
#include <hip/hip_runtime.h>

#define COUT_  128
#define KP     1024          // K layout: (cin>>2)*64 + k*4 + (cin&3); k>=9 -> pad zeros
#define CAPR   20            // img rows loaded (span>20: P ~ 1e-6); +1 zero pad row
#define IMGC   (21 * 64)     // u32 per cin plane (20 rows + pad row)
#define IMGBUF (4 * IMGC)    // per group buffer
#define COLU   37            // u32 per px per col buf; 37 (not 36): px*37 mod 32 covers all
                             // banks -> col uint2 writes conflict-free (36 hit 16 banks, 2x)
#define COLBUF (64 * COLU)

#if __has_builtin(__builtin_amdgcn_fdot2_f32_bf16)
#define HAS_DOT2 1
#else
#define HAS_DOT2 0
#endif

typedef __attribute__((ext_vector_type(8))) __bf16 bf16x8;
typedef __attribute__((ext_vector_type(2))) __bf16 bf16x2;
typedef unsigned short u16x8 __attribute__((ext_vector_type(8)));
typedef __attribute__((ext_vector_type(4))) float f32x4;

__device__ __forceinline__ unsigned int f2bf(float f) {
    union { float f; unsigned int u; } c; c.f = f;
    unsigned int u = c.u;
    u += 0x7fffu + ((u >> 16) & 1u);   // RNE
    return u >> 16;
}
__device__ __forceinline__ float bitsf(unsigned int u) {
    union { unsigned int u; float f; } c; c.u = u; return c.f;
}
// paired f32->bf16 via compiler casts (RNE; compiler emits packed cvt where profitable)
__device__ __forceinline__ unsigned int pk2bf(float lo, float hi) {
    bf16x2 v;
    v[0] = (__bf16)lo;
    v[1] = (__bf16)hi;
    return __builtin_bit_cast(unsigned int, v);
}
__device__ __forceinline__ bf16x2 mk_bf2(float lo, float hi) {
    bf16x2 v;
    v[0] = (__bf16)lo;
    v[1] = (__bf16)hi;
    return v;
}

// Wbf[cout][KP], K = (cin>>2)*64 + k*4 + (cin&3); 4 entries/thread, one ushort4 store.
__global__ void prep_w(const float* __restrict__ w, unsigned short* __restrict__ wbf) {
    const int base = (blockIdx.x * 256 + threadIdx.x) * 4;   // 128 blocks: 32768*4 = COUT_*KP
    const int cout = base >> 10, r = base & 1023;
    const int quad = r >> 6, j2 = r & 63;
    const int k = j2 >> 2;
    ushort4 v = make_ushort4(0, 0, 0, 0);
    if (k < 9) {
        const float* wp = w + (cout * 64 + quad * 4) * 9 + k;
        v.x = (unsigned short)f2bf(wp[0]);
        v.y = (unsigned short)f2bf(wp[9]);
        v.z = (unsigned short)f2bf(wp[18]);
        v.w = (unsigned short)f2bf(wp[27]);
    }
    *(ushort4*)(wbf + base) = v;
}

__launch_bounds__(256, 2)
__global__ void deform_mfma6(const float* __restrict__ rgb,
                             const float* __restrict__ off,
                             const unsigned short* __restrict__ wbf,
                             const float* __restrict__ bias,
                             float* __restrict__ out) {
    // [col dbuf: 2x2368 u32][img dbuf: 2x5376 u32] = 62464 B
    __shared__ unsigned int S[2 * COLBUF + 2 * IMGBUF];
    __shared__ int sW[8];
    unsigned int* imgU = S + 2 * COLBUF;

    const int t    = threadIdx.x;
    const int bid  = blockIdx.x;
    const int b    = bid & 7;          // XCD pin
    const int ho   = bid >> 3;
    const int lane = t & 63;
    const int wv   = t >> 6;
    const int px   = lane;
    const int ln15 = lane & 15;
    const int q    = lane >> 4;

    const float* offb = off + b * (2 * 9 * 4096);

    // ---- meta A first: offset loads issue before anything else ----
    float m_fy[3], m_fx[3]; int m_y0[3], m_x0[3];
    int lmin = 64, lmax = -1;
#pragma unroll
    for (int ti = 0; ti < 3; ti++) {
        const int kt = (ti < 2) ? (wv + ti * 4) : 8;
        const float dy = offb[((2 * kt)     * 64 + ho) * 64 + px];
        const float dx = offb[((2 * kt + 1) * 64 + ho) * 64 + px];
        const float y = (float)(ho - 1 + kt / 3) + dy;
        const float x = (float)(px - 1 + kt % 3) + dx;
        const float y0f = floorf(y), x0f = floorf(x);
        m_fy[ti] = y - y0f; m_fx[ti] = x - x0f;
        m_y0[ti] = (int)y0f; m_x0[ti] = (int)x0f;
        const int r0 = min(max(m_y0[ti], 0), 63), r1 = min(max(m_y0[ti] + 1, 0), 63);
        lmin = min(lmin, r0); lmax = max(lmax, r1);
    }
    // wave-level reduce (no shared atomics, one barrier)
#pragma unroll
    for (int d = 1; d < 64; d <<= 1) {
        lmin = min(lmin, __shfl_xor(lmin, d));
        lmax = max(lmax, __shfl_xor(lmax, d));
    }
    if (lane == 0) { sW[wv] = lmin; sW[4 + wv] = lmax; }
    __syncthreads();
    const int ymin  = min(min(sW[0], sW[1]), min(sW[2], sW[3]));
    const int ymax  = max(max(sW[4], sW[5]), max(sW[6], sW[7]));
    const int nrows = ymax - ymin + 1;
    const int nr4   = min((nrows + 3) & ~3, CAPR);
    const int ymin2 = max(0, min(ymin, 64 - nr4));

    // ---- targeted pad zeroing ----
    // col: mfma reads u16[0..63] (u32[0..31]); gather writes u32[0..17] every
    // iter before any read, so zero u32[16..31] per px, both buffers.
    // img: interp reads rows <= nr4; staging fills rows [0,nr4), so zero row nr4
    // of each plane, both buffers.
    {
        const uint4 z4 = make_uint4(0, 0, 0, 0);
        for (int i = t; i < 512; i += 256) {               // 2 buf * 64 px * 4 uint4
            const int buf = i >> 8, j = i & 255, p_ = j >> 2, r = j & 3;
            *(uint4*)&S[buf * COLBUF + p_ * COLU + 16 + r * 4] = z4;
        }
        if (t < 128) {                                      // 2 buf * 4 planes * 16 uint4
            const int buf = t >> 6, pl = (t >> 4) & 3, c4 = t & 15;
            *(uint4*)&imgU[buf * IMGBUF + pl * IMGC + nr4 * 64 + c4 * 4] = z4;
        }
    }

    // ---- staging: reg path (T14 split: load early, write late) ----
    float4 sv[5];
    auto stage_load = [&](int gg) {
        const float* gp = rgb + ((unsigned)(b * 64 + gg * 4 + wv) * 64 + ymin2 + (lane >> 4)) * 64 + (lane & 15) * 4;
#pragma unroll
        for (int n = 0; n < 5; n++)                         // static index: no scratch
            if (n * 4 < nr4) sv[n] = *(const float4*)(gp + n * 4 * 64);
    };
    auto stage_write = [&](int gg) {
        unsigned int* lp = imgU + (gg & 1) * IMGBUF + wv * IMGC + (lane >> 4) * 64 + (lane & 15) * 4;
#pragma unroll
        for (int n = 0; n < 5; n++) {
            if (n * 4 < nr4) {
                const float4 v = sv[n];
                float nf = __shfl(v.x, lane + 1);
                if ((lane & 15) == 15) nf = 0.f;
                uint4 pk;
                pk.x = pk2bf(v.x, v.y); pk.y = pk2bf(v.y, v.z);
                pk.z = pk2bf(v.z, v.w); pk.w = pk2bf(v.w, nf);
                *(uint4*)(lp + n * 4 * 64) = pk;
            }
        }
    };

    // ---- meta B: one LDS offset per tap (r1 = r0+1 forced) + packed weights ----
    int ma[3];
#if HAS_DOT2
    bf16x2 wtp[3], wbp[3];
#else
    float mw[3][4];
#endif
#pragma unroll
    for (int ti = 0; ti < 3; ti++) {
        const int y0 = m_y0[ti], x0 = m_x0[ti];
        const float fy = m_fy[ti], fx = m_fx[ti];
        const int r0 = y0 - ymin2;
        const float wy0 = (y0 >= 0  && y0 < 64) ? (1.f - fy) : 0.f;
        const float wy1 = (y0 >= -1 && y0 < 63) ? fy         : 0.f;
        const bool ylo = (r0 < 0);
        const float wtop = ylo ? wy1 : wy0;
        const float wbot = ylo ? 0.f : wy1;
        const int r0c = ylo ? 0 : min(r0, nr4 - 1);
        const float wx0 = (x0 >= 0  && x0 < 64) ? (1.f - fx) : 0.f;
        const float wx1 = (x0 >= -1 && x0 < 63) ? fx         : 0.f;
        const bool xlo = (x0 < 0);
        const float wA = xlo ? wx1 : wx0;
        const float wB = xlo ? 0.f : wx1;
        const int xc = min(max(x0, 0), 63);
        ma[ti] = r0c * 64 + xc;
#if HAS_DOT2
        wtp[ti] = mk_bf2(wtop * wA, wtop * wB);
        wbp[ti] = mk_bf2(wbot * wA, wbot * wB);
#else
        mw[ti][0] = wtop * wA; mw[ti][1] = wtop * wB;
        mw[ti][2] = wbot * wA; mw[ti][3] = wbot * wB;
#endif
    }

    f32x4 acc[2][4] = {};
    const unsigned short* wrow0 = wbf + (wv * 32 + ln15) * KP;
    const unsigned short* wrow1 = wrow0 + 16 * KP;
    const unsigned short* col16 = (const unsigned short*)S;

    auto interp1 = [&](const unsigned int* pl, int ti) -> float {
        const unsigned int* p = pl + ma[ti];
        const unsigned int tp = p[0];     // rows r0c, r0c+1: const delta 256B
        const unsigned int bp = p[64];    // -> ds_read2_b32 offset0:0 offset1:64
#if HAS_DOT2
        float r = __builtin_amdgcn_fdot2_f32_bf16(__builtin_bit_cast(bf16x2, tp), wtp[ti], 0.f, false);
        return  __builtin_amdgcn_fdot2_f32_bf16(__builtin_bit_cast(bf16x2, bp), wbp[ti], r, false);
#else
        return mw[ti][0] * bitsf(tp << 16) + mw[ti][1] * bitsf(tp & 0xffff0000u)
             + mw[ti][2] * bitsf(bp << 16) + mw[ti][3] * bitsf(bp & 0xffff0000u);
#endif
    };
    auto gather = [&](int g) {
        const unsigned int* ib = imgU + (g & 1) * IMGBUF;
        unsigned int* cb = S + (g & 1) * COLBUF + px * COLU;
#pragma unroll
        for (int ti = 0; ti < 2; ti++) {
            const int kt = wv + ti * 4;
            uint2 w2;
            w2.x = pk2bf(interp1(ib, ti),            interp1(ib + IMGC, ti));
            w2.y = pk2bf(interp1(ib + 2 * IMGC, ti), interp1(ib + 3 * IMGC, ti));
            *(uint2*)&cb[kt * 2] = w2;
        }
        if (wv == (g & 3))
            cb[16] = pk2bf(interp1(ib, 2),            interp1(ib + IMGC, 2));
        if (wv == ((g + 2) & 3))
            cb[17] = pk2bf(interp1(ib + 2 * IMGC, 2), interp1(ib + 3 * IMGC, 2));
    };
    auto mfma_steps = [&](int gg) {
#pragma unroll
        for (int sg = 0; sg < 2; sg++) {
            const int s = 2 * gg + sg;
            const u16x8 a0u = *(const u16x8*)(wrow0 + s * 32 + q * 8);
            const u16x8 a1u = *(const u16x8*)(wrow1 + s * 32 + q * 8);
            const bf16x8 a0 = __builtin_bit_cast(bf16x8, a0u);
            const bf16x8 a1 = __builtin_bit_cast(bf16x8, a1u);
#pragma unroll
            for (int nj = 0; nj < 4; nj++) {
                const u16x8 bu = *(const u16x8*)(col16 + (gg & 1) * (COLBUF * 2)
                                                 + (nj * 16 + ln15) * (COLU * 2) + sg * 32 + q * 8);
                const bf16x8 bv = __builtin_bit_cast(bf16x8, bu);
                acc[0][nj] = __builtin_amdgcn_mfma_f32_16x16x32_bf16(a0, bv, acc[0][nj], 0, 0, 0);
                acc[1][nj] = __builtin_amdgcn_mfma_f32_16x16x32_bf16(a1, bv, acc[1][nj], 0, 0, 0);
            }
        }
    };

    stage_load(0); stage_write(0);
    __syncthreads();

    for (int g = 0; g < 16; g++) {
        if (g + 1 < 16) stage_load(g + 1);
        gather(g);
        if (g > 0) mfma_steps(g - 1);
        if (g + 1 < 16) stage_write(g + 1);
        __syncthreads();
    }
    mfma_steps(15);

#pragma unroll
    for (int mi = 0; mi < 2; mi++) {
#pragma unroll
        for (int r = 0; r < 4; r++) {
            const int cout = wv * 32 + mi * 16 + q * 4 + r;
            const float bv = bias[cout];
            float* orow = out + ((b * COUT_ + cout) * 64 + ho) * 64;
#pragma unroll
            for (int nj = 0; nj < 4; nj++)
                orow[nj * 16 + ln15] = acc[mi][nj][r] + bv;
        }
    }
}

extern "C" void kernel_launch(void* const* d_in, const int* in_sizes, int n_in,
                              void* d_out, int out_size, void* d_ws, size_t ws_size,
                              hipStream_t stream) {
    const float* rgb  = (const float*)d_in[0];
    const float* off  = (const float*)d_in[1];
    const float* w    = (const float*)d_in[2];
    const float* bias = (const float*)d_in[3];
    float* out = (float*)d_out;
    unsigned short* wbf = (unsigned short*)d_ws;   // 256 KB used

    prep_w<<<COUT_ * KP / 1024, 256, 0, stream>>>(w, wbf);
    deform_mfma6<<<512, 256, 0, stream>>>(rgb, off, wbf, bias, out);
}

// Round 7
// 95.484 us; speedup vs baseline: 1.2422x; 1.2422x over previous
//
#include <hip/hip_runtime.h>

#define COUT_  128
#define KP     1024          // K layout: (cin>>2)*64 + k*4 + (cin&3); k>=9 -> pad zeros
#define CAPR   20            // img rows loaded (span>20: P ~ 1e-6); +1 zero pad row
#define IMGC   (21 * 64)     // u32 per cin plane (20 rows + pad row)
#define IMGBUF (4 * IMGC)    // per group buffer
#define COLU   36            // u32 per px per col buf (72 u16 = 144B row). MUST stay 36:
                             // 37 broke 16B align of b128 B-reads -> DS split, +21us (round 6)
#define COLBUF (64 * COLU)

#if __has_builtin(__builtin_amdgcn_fdot2_f32_bf16)
#define HAS_DOT2 1
#else
#define HAS_DOT2 0
#endif

typedef __attribute__((ext_vector_type(8))) __bf16 bf16x8;
typedef __attribute__((ext_vector_type(2))) __bf16 bf16x2;
typedef unsigned short u16x8 __attribute__((ext_vector_type(8)));
typedef __attribute__((ext_vector_type(4))) float f32x4;

__device__ __forceinline__ unsigned int f2bf(float f) {
    union { float f; unsigned int u; } c; c.f = f;
    unsigned int u = c.u;
    u += 0x7fffu + ((u >> 16) & 1u);   // RNE
    return u >> 16;
}
__device__ __forceinline__ float bitsf(unsigned int u) {
    union { unsigned int u; float f; } c; c.u = u; return c.f;
}
// paired f32->bf16 via compiler casts (RNE; compiler emits packed cvt where profitable)
__device__ __forceinline__ unsigned int pk2bf(float lo, float hi) {
    bf16x2 v;
    v[0] = (__bf16)lo;
    v[1] = (__bf16)hi;
    return __builtin_bit_cast(unsigned int, v);
}
__device__ __forceinline__ bf16x2 mk_bf2(float lo, float hi) {
    bf16x2 v;
    v[0] = (__bf16)lo;
    v[1] = (__bf16)hi;
    return v;
}

// Raw barrier: lgkmcnt(0) only (publish LDS writes). NO vmcnt drain — staged
// global loads live in registers across the barrier (2-deep sv pipeline);
// their only consumer is this wave's stage_write, where the compiler inserts
// the per-register vmcnt wait. sched_barrier(0) fences code motion (rule #18).
__device__ __forceinline__ void barx() {
    __builtin_amdgcn_sched_barrier(0);
    asm volatile("s_waitcnt lgkmcnt(0)" ::: "memory");
    __builtin_amdgcn_s_barrier();
    __builtin_amdgcn_sched_barrier(0);
}

// Wbf[cout][KP], K = (cin>>2)*64 + k*4 + (cin&3); 4 entries/thread, one ushort4 store.
__global__ void prep_w(const float* __restrict__ w, unsigned short* __restrict__ wbf) {
    const int base = (blockIdx.x * 256 + threadIdx.x) * 4;   // 128 blocks: 32768*4 = COUT_*KP
    const int cout = base >> 10, r = base & 1023;
    const int quad = r >> 6, j2 = r & 63;
    const int k = j2 >> 2;
    ushort4 v = make_ushort4(0, 0, 0, 0);
    if (k < 9) {
        const float* wp = w + (cout * 64 + quad * 4) * 9 + k;
        v.x = (unsigned short)f2bf(wp[0]);
        v.y = (unsigned short)f2bf(wp[9]);
        v.z = (unsigned short)f2bf(wp[18]);
        v.w = (unsigned short)f2bf(wp[27]);
    }
    *(ushort4*)(wbf + base) = v;
}

__launch_bounds__(256, 2)
__global__ void deform_mfma6(const float* __restrict__ rgb,
                             const float* __restrict__ off,
                             const unsigned short* __restrict__ wbf,
                             const float* __restrict__ bias,
                             float* __restrict__ out) {
    // [col dbuf: 2x2304 u32][img dbuf: 2x5376 u32] = 61440 B
    __shared__ unsigned int S[2 * COLBUF + 2 * IMGBUF];
    __shared__ int sW[8];
    unsigned int* imgU = S + 2 * COLBUF;

    const int t    = threadIdx.x;
    const int bid  = blockIdx.x;
    const int b    = bid & 7;          // XCD pin
    const int ho   = bid >> 3;
    const int lane = t & 63;
    const int wv   = t >> 6;
    const int px   = lane;
    const int ln15 = lane & 15;
    const int q    = lane >> 4;

    const float* offb = off + b * (2 * 9 * 4096);

    // ---- meta A first: offset loads issue before anything else ----
    float m_fy[3], m_fx[3]; int m_y0[3], m_x0[3];
    int lmin = 64, lmax = -1;
#pragma unroll
    for (int ti = 0; ti < 3; ti++) {
        const int kt = (ti < 2) ? (wv + ti * 4) : 8;
        const float dy = offb[((2 * kt)     * 64 + ho) * 64 + px];
        const float dx = offb[((2 * kt + 1) * 64 + ho) * 64 + px];
        const float y = (float)(ho - 1 + kt / 3) + dy;
        const float x = (float)(px - 1 + kt % 3) + dx;
        const float y0f = floorf(y), x0f = floorf(x);
        m_fy[ti] = y - y0f; m_fx[ti] = x - x0f;
        m_y0[ti] = (int)y0f; m_x0[ti] = (int)x0f;
        const int r0 = min(max(m_y0[ti], 0), 63), r1 = min(max(m_y0[ti] + 1, 0), 63);
        lmin = min(lmin, r0); lmax = max(lmax, r1);
    }
    // wave-level reduce (no shared atomics, one barrier)
#pragma unroll
    for (int d = 1; d < 64; d <<= 1) {
        lmin = min(lmin, __shfl_xor(lmin, d));
        lmax = max(lmax, __shfl_xor(lmax, d));
    }
    if (lane == 0) { sW[wv] = lmin; sW[4 + wv] = lmax; }
    __syncthreads();
    const int ymin  = min(min(sW[0], sW[1]), min(sW[2], sW[3]));
    const int ymax  = max(max(sW[4], sW[5]), max(sW[6], sW[7]));
    const int nrows = ymax - ymin + 1;
    const int nr4   = min((nrows + 3) & ~3, CAPR);
    const int ymin2 = max(0, min(ymin, 64 - nr4));

    // ---- staging: 2-deep reg pipeline (group k: load in interval k-2, LDS-write
    //      in interval k-1). Even groups -> svA, odd -> svB. ----
    float4 svA[5], svB[5];
    auto stage_load = [&](int gg, float4 (&sv)[5]) {
        const float* gp = rgb + ((unsigned)(b * 64 + gg * 4 + wv) * 64 + ymin2 + (lane >> 4)) * 64 + (lane & 15) * 4;
#pragma unroll
        for (int n = 0; n < 5; n++)                         // static index: no scratch
            if (n * 4 < nr4) sv[n] = *(const float4*)(gp + n * 4 * 64);
    };
    auto stage_write = [&](int gg, float4 (&sv)[5]) {
        unsigned int* lp = imgU + (gg & 1) * IMGBUF + wv * IMGC + (lane >> 4) * 64 + (lane & 15) * 4;
#pragma unroll
        for (int n = 0; n < 5; n++) {
            if (n * 4 < nr4) {
                const float4 v = sv[n];
                float nf = __shfl(v.x, lane + 1);
                if ((lane & 15) == 15) nf = 0.f;
                uint4 pk;
                pk.x = pk2bf(v.x, v.y); pk.y = pk2bf(v.y, v.z);
                pk.z = pk2bf(v.z, v.w); pk.w = pk2bf(v.w, nf);
                *(uint4*)(lp + n * 4 * 64) = pk;
            }
        }
    };

    // issue the first two groups' loads ASAP: zeroing + meta-B hide their latency
    stage_load(0, svA);
    stage_load(1, svB);

    // ---- targeted pad zeroing ----
    // col: mfma reads u16[0..63] (u32[0..31]); gather writes u32[0..17] every
    // iter before any read, so zero u32[16..31] per px, both buffers.
    // img: interp reads rows <= nr4; staging fills rows [0,nr4), so zero row nr4
    // of each plane, both buffers.
    {
        const uint4 z4 = make_uint4(0, 0, 0, 0);
        for (int i = t; i < 512; i += 256) {               // 2 buf * 64 px * 4 uint4
            const int buf = i >> 8, j = i & 255, p_ = j >> 2, r = j & 3;
            *(uint4*)&S[buf * COLBUF + p_ * COLU + 16 + r * 4] = z4;
        }
        if (t < 128) {                                      // 2 buf * 4 planes * 16 uint4
            const int buf = t >> 6, pl = (t >> 4) & 3, c4 = t & 15;
            *(uint4*)&imgU[buf * IMGBUF + pl * IMGC + nr4 * 64 + c4 * 4] = z4;
        }
    }

    // ---- meta B: one LDS offset per tap (r1 = r0+1 forced) + packed weights ----
    int ma[3];
#if HAS_DOT2
    bf16x2 wtp[3], wbp[3];
#else
    float mw[3][4];
#endif
#pragma unroll
    for (int ti = 0; ti < 3; ti++) {
        const int y0 = m_y0[ti], x0 = m_x0[ti];
        const float fy = m_fy[ti], fx = m_fx[ti];
        const int r0 = y0 - ymin2;
        const float wy0 = (y0 >= 0  && y0 < 64) ? (1.f - fy) : 0.f;
        const float wy1 = (y0 >= -1 && y0 < 63) ? fy         : 0.f;
        const bool ylo = (r0 < 0);
        const float wtop = ylo ? wy1 : wy0;
        const float wbot = ylo ? 0.f : wy1;
        const int r0c = ylo ? 0 : min(r0, nr4 - 1);
        const float wx0 = (x0 >= 0  && x0 < 64) ? (1.f - fx) : 0.f;
        const float wx1 = (x0 >= -1 && x0 < 63) ? fx         : 0.f;
        const bool xlo = (x0 < 0);
        const float wA = xlo ? wx1 : wx0;
        const float wB = xlo ? 0.f : wx1;
        const int xc = min(max(x0, 0), 63);
        ma[ti] = r0c * 64 + xc;
#if HAS_DOT2
        wtp[ti] = mk_bf2(wtop * wA, wtop * wB);
        wbp[ti] = mk_bf2(wbot * wA, wbot * wB);
#else
        mw[ti][0] = wtop * wA; mw[ti][1] = wtop * wB;
        mw[ti][2] = wbot * wA; mw[ti][3] = wbot * wB;
#endif
    }

    f32x4 acc[2][4] = {};
    const unsigned short* wrow0 = wbf + (wv * 32 + ln15) * KP;
    const unsigned short* wrow1 = wrow0 + 16 * KP;
    const unsigned short* col16 = (const unsigned short*)S;

    auto interp1 = [&](const unsigned int* pl, int ti) -> float {
        const unsigned int* p = pl + ma[ti];
        const unsigned int tp = p[0];     // rows r0c, r0c+1: const delta 256B
        const unsigned int bp = p[64];    // -> ds_read2_b32 offset0:0 offset1:64
#if HAS_DOT2
        float r = __builtin_amdgcn_fdot2_f32_bf16(__builtin_bit_cast(bf16x2, tp), wtp[ti], 0.f, false);
        return  __builtin_amdgcn_fdot2_f32_bf16(__builtin_bit_cast(bf16x2, bp), wbp[ti], r, false);
#else
        return mw[ti][0] * bitsf(tp << 16) + mw[ti][1] * bitsf(tp & 0xffff0000u)
             + mw[ti][2] * bitsf(bp << 16) + mw[ti][3] * bitsf(bp & 0xffff0000u);
#endif
    };
    auto gather = [&](int g) {
        const unsigned int* ib = imgU + (g & 1) * IMGBUF;
        unsigned int* cb = S + (g & 1) * COLBUF + px * COLU;
#pragma unroll
        for (int ti = 0; ti < 2; ti++) {
            const int kt = wv + ti * 4;
            uint2 w2;
            w2.x = pk2bf(interp1(ib, ti),            interp1(ib + IMGC, ti));
            w2.y = pk2bf(interp1(ib + 2 * IMGC, ti), interp1(ib + 3 * IMGC, ti));
            *(uint2*)&cb[kt * 2] = w2;
        }
        if (wv == (g & 3))
            cb[16] = pk2bf(interp1(ib, 2),            interp1(ib + IMGC, 2));
        if (wv == ((g + 2) & 3))
            cb[17] = pk2bf(interp1(ib + 2 * IMGC, 2), interp1(ib + 3 * IMGC, 2));
    };
    auto mfma_steps = [&](int gg) {
#pragma unroll
        for (int sg = 0; sg < 2; sg++) {
            const int s = 2 * gg + sg;
            const u16x8 a0u = *(const u16x8*)(wrow0 + s * 32 + q * 8);
            const u16x8 a1u = *(const u16x8*)(wrow1 + s * 32 + q * 8);
            const bf16x8 a0 = __builtin_bit_cast(bf16x8, a0u);
            const bf16x8 a1 = __builtin_bit_cast(bf16x8, a1u);
#pragma unroll
            for (int nj = 0; nj < 4; nj++) {
                const u16x8 bu = *(const u16x8*)(col16 + (gg & 1) * (COLBUF * 2)
                                                 + (nj * 16 + ln15) * (COLU * 2) + sg * 32 + q * 8);
                const bf16x8 bv = __builtin_bit_cast(bf16x8, bu);
                acc[0][nj] = __builtin_amdgcn_mfma_f32_16x16x32_bf16(a0, bv, acc[0][nj], 0, 0, 0);
                acc[1][nj] = __builtin_amdgcn_mfma_f32_16x16x32_bf16(a1, bv, acc[1][nj], 0, 0, 0);
            }
        }
    };

    stage_write(0, svA);     // waits svA's loads via register deps only
    barx();

    // Per interval g: gather(g) [reads img g&1], mfma(g-1) [reads col (g-1)&1],
    // stage_write(g+1) [regs loaded last interval], stage_load(g+2) [across barrier].
    for (int g = 0; g < 16; g += 2) {
        // even interval
        if (g + 2 < 16) stage_load(g + 2, svA);
        gather(g);
        if (g > 0) mfma_steps(g - 1);
        stage_write(g + 1, svB);
        barx();
        // odd interval
        if (g + 3 < 16) stage_load(g + 3, svB);
        gather(g + 1);
        mfma_steps(g);
        if (g + 2 < 16) stage_write(g + 2, svA);
        barx();
    }
    mfma_steps(15);

#pragma unroll
    for (int mi = 0; mi < 2; mi++) {
#pragma unroll
        for (int r = 0; r < 4; r++) {
            const int cout = wv * 32 + mi * 16 + q * 4 + r;
            const float bv = bias[cout];
            float* orow = out + ((b * COUT_ + cout) * 64 + ho) * 64;
#pragma unroll
            for (int nj = 0; nj < 4; nj++)
                orow[nj * 16 + ln15] = acc[mi][nj][r] + bv;
        }
    }
}

extern "C" void kernel_launch(void* const* d_in, const int* in_sizes, int n_in,
                              void* d_out, int out_size, void* d_ws, size_t ws_size,
                              hipStream_t stream) {
    const float* rgb  = (const float*)d_in[0];
    const float* off  = (const float*)d_in[1];
    const float* w    = (const float*)d_in[2];
    const float* bias = (const float*)d_in[3];
    float* out = (float*)d_out;
    unsigned short* wbf = (unsigned short*)d_ws;   // 256 KB used

    prep_w<<<COUT_ * KP / 1024, 256, 0, stream>>>(w, wbf);
    deform_mfma6<<<512, 256, 0, stream>>>(rgb, off, wbf, bias, out);
}